// Round 7
// baseline (104.386 us; speedup 1.0000x reference)
//
#include <hip/hip_runtime.h>
#include <math.h>

// Problem constants
constexpr int Bb = 8;     // batch
constexpr int Ns = 1024;  // tokens (32x32)
constexpr int Es = 256;   // embed
constexpr int NH = 8;     // heads
constexpr int DH = 32;    // head dim
constexpr int Mrows = Bb * Ns;        // 8192
constexpr int NX = Mrows * Es;        // 2097152

typedef __bf16 bf16x8 __attribute__((ext_vector_type(8)));
typedef float  f32x4  __attribute__((ext_vector_type(4)));
union U4B8 { uint4 u; bf16x8 b; unsigned short s[8]; };

__device__ __forceinline__ unsigned short f2bf(float f) {
    union { float f; unsigned u; } c; c.f = f;
    unsigned r = (c.u + 0x7FFFu + ((c.u >> 16) & 1u)) >> 16;
    return (unsigned short)r;
}
__device__ __forceinline__ float bf2f(unsigned short h) {
    union { unsigned u; float f; } c; c.u = ((unsigned)h) << 16;
    return c.f;
}

#define GLD 72    // gemm LDS row stride (bf16)
#define PST 232   // attn P row stride (bf16)

// ---------------------------------------------------------------------------
// Ledger: persistence -237 (grid barrier 60-110us each), occupancy +-0,
// no-LDS GEMM -21 (16-row scatter), attn+proj fusion -3 (parallelism loss).
// Time model: dur ~= poison-fill(41us, harness, timed) + kernels + small gaps.
// R7: delete cast_all by folding fp32->bf16 casts INTO GEMM LDS staging.
// Old session's "re-cast 12-128x is worse" verdict is void here: VALUBusy is
// 2.6% measured -> redundant cast VALU ~1us chip-wide, free; extra fp32 L2/L3
// read traffic ~+1.5us < deleted dispatch (~5-8us exec + gap).
// GEMMs at (256,4): staging holds 32 fp32 transients (VGPR ~110 < 128 cap).
// Attention kernel byte-identical to R4's verified version.
// ---------------------------------------------------------------------------

// ---------------------------------------------------------------------------
// Kernel 1: QKV GEMM, fp32 inputs, cast-on-stage. 64x64 tile, BK=64.
// ---------------------------------------------------------------------------
__global__ __launch_bounds__(256, 4)
void qkv_gemm(const float* __restrict__ A, const float* __restrict__ W,
              const float* __restrict__ qkv_b,
              unsigned short* __restrict__ qo, unsigned short* __restrict__ ko,
              unsigned short* __restrict__ vto)
{
    __shared__ unsigned short As[64 * GLD];
    __shared__ unsigned short Ws[64 * GLD];

    const int t = threadIdx.x;
    const int m0 = (blockIdx.x & 127) * 64;
    const int j0 = (blockIdx.x >> 7) * 64;

    const int srow = t >> 2;
    const int scol = (t & 3) * 16;

    const int lane = t & 63;
    const int wave = t >> 6;
    const int wm = (wave & 1) * 32;
    const int wn = (wave >> 1) * 32;
    const int fm = lane & 15;
    const int fq = lane >> 4;

    f32x4 acc[2][2];
    #pragma unroll
    for (int i = 0; i < 2; i++)
        #pragma unroll
        for (int j = 0; j < 2; j++)
            acc[i][j] = (f32x4){0.f, 0.f, 0.f, 0.f};

    const float* Arow = A + (size_t)(m0 + srow) * Es;
    const float* Wrow = W + (size_t)(j0 + srow) * Es;

    for (int k0 = 0; k0 < Es; k0 += 64) {
        float4 a0 = *(const float4*)(Arow + k0 + scol);
        float4 a1 = *(const float4*)(Arow + k0 + scol + 4);
        float4 a2 = *(const float4*)(Arow + k0 + scol + 8);
        float4 a3 = *(const float4*)(Arow + k0 + scol + 12);
        float4 w0 = *(const float4*)(Wrow + k0 + scol);
        float4 w1 = *(const float4*)(Wrow + k0 + scol + 4);
        float4 w2 = *(const float4*)(Wrow + k0 + scol + 8);
        float4 w3 = *(const float4*)(Wrow + k0 + scol + 12);
        U4B8 ap0, ap1, wp0, wp1;
        ap0.s[0] = f2bf(a0.x); ap0.s[1] = f2bf(a0.y); ap0.s[2] = f2bf(a0.z); ap0.s[3] = f2bf(a0.w);
        ap0.s[4] = f2bf(a1.x); ap0.s[5] = f2bf(a1.y); ap0.s[6] = f2bf(a1.z); ap0.s[7] = f2bf(a1.w);
        ap1.s[0] = f2bf(a2.x); ap1.s[1] = f2bf(a2.y); ap1.s[2] = f2bf(a2.z); ap1.s[3] = f2bf(a2.w);
        ap1.s[4] = f2bf(a3.x); ap1.s[5] = f2bf(a3.y); ap1.s[6] = f2bf(a3.z); ap1.s[7] = f2bf(a3.w);
        wp0.s[0] = f2bf(w0.x); wp0.s[1] = f2bf(w0.y); wp0.s[2] = f2bf(w0.z); wp0.s[3] = f2bf(w0.w);
        wp0.s[4] = f2bf(w1.x); wp0.s[5] = f2bf(w1.y); wp0.s[6] = f2bf(w1.z); wp0.s[7] = f2bf(w1.w);
        wp1.s[0] = f2bf(w2.x); wp1.s[1] = f2bf(w2.y); wp1.s[2] = f2bf(w2.z); wp1.s[3] = f2bf(w2.w);
        wp1.s[4] = f2bf(w3.x); wp1.s[5] = f2bf(w3.y); wp1.s[6] = f2bf(w3.z); wp1.s[7] = f2bf(w3.w);
        __syncthreads();
        *(uint4*)&As[srow * GLD + scol]     = ap0.u;
        *(uint4*)&As[srow * GLD + scol + 8] = ap1.u;
        *(uint4*)&Ws[srow * GLD + scol]     = wp0.u;
        *(uint4*)&Ws[srow * GLD + scol + 8] = wp1.u;
        __syncthreads();
        #pragma unroll
        for (int ks = 0; ks < 64; ks += 32) {
            U4B8 af0, af1, bf0, bf1;
            af0.u = *(const uint4*)&As[(wm +      fm) * GLD + ks + fq * 8];
            af1.u = *(const uint4*)&As[(wm + 16 + fm) * GLD + ks + fq * 8];
            bf0.u = *(const uint4*)&Ws[(wn +      fm) * GLD + ks + fq * 8];
            bf1.u = *(const uint4*)&Ws[(wn + 16 + fm) * GLD + ks + fq * 8];
            acc[0][0] = __builtin_amdgcn_mfma_f32_16x16x32_bf16(af0.b, bf0.b, acc[0][0], 0, 0, 0);
            acc[0][1] = __builtin_amdgcn_mfma_f32_16x16x32_bf16(af0.b, bf1.b, acc[0][1], 0, 0, 0);
            acc[1][0] = __builtin_amdgcn_mfma_f32_16x16x32_bf16(af1.b, bf0.b, acc[1][0], 0, 0, 0);
            acc[1][1] = __builtin_amdgcn_mfma_f32_16x16x32_bf16(af1.b, bf1.b, acc[1][1], 0, 0, 0);
        }
    }

    // C/D: col = lane&15, row = quad*4 + reg
    #pragma unroll
    for (int mt = 0; mt < 2; mt++) {
        #pragma unroll
        for (int nt = 0; nt < 2; nt++) {
            #pragma unroll
            for (int r = 0; r < 4; r++) {
                int row = m0 + wm + mt * 16 + fq * 4 + r;
                int col = j0 + wn + nt * 16 + fm;
                float val = acc[mt][nt][r] + qkv_b[col];
                int part = col >> 8;           // 0:q 1:k 2:v
                int head = (col >> 5) & 7;
                int d = col & 31;
                int b = row >> 10;
                int n = row & 1023;
                int bh = b * NH + head;
                if (part == 0)
                    qo[((size_t)bh * Ns + n) * DH + d] = f2bf(val * 0.0625f);
                else if (part == 1)
                    ko[((size_t)bh * Ns + n) * DH + d] = f2bf(val);
                else
                    vto[((size_t)bh * DH + d) * Ns + n] = f2bf(val);
            }
        }
    }
}

// ---------------------------------------------------------------------------
// Kernel 2: MFMA attention (byte-identical to R4-verified version).
// ---------------------------------------------------------------------------
__global__ __launch_bounds__(256, 6)
void attn_mfma2(const unsigned short* __restrict__ qb, const unsigned short* __restrict__ kb,
                const unsigned short* __restrict__ vtb, unsigned short* __restrict__ aob)
{
    __shared__ unsigned short Pb[32 * PST];   // 14848 B
    __shared__ float psum[2][32];

    const int blk = blockIdx.x;          // 0..2047
    const int b   = blk & 7;             // XCD-locality: batch pinned to XCD
    const int u   = blk >> 3;
    const int h   = u & 7;
    const int hq  = u >> 3;
    const int bh  = b * NH + h;

    const int t   = threadIdx.x;
    const int lane = t & 63;
    const int w    = t >> 6;
    const int fm = lane & 15;
    const int fq = lane >> 4;

    int n0c = (hq - 3) * 32;
    n0c = n0c < 0 ? 0 : (n0c > Ns - 224 ? Ns - 224 : n0c);

    const int qbase = (w & 1) * 16;      // query 16-tile
    const int sel   = w >> 1;            // key-tile parity
    const int dbase = (w >> 1) * 16;     // PV dim-tile

    // V^T fragment prefetch (B-operand: n=dim, k=key)
    const unsigned short* vrow = vtb + ((size_t)bh * DH + dbase + fm) * Ns;
    uint4 vpre[7];
    #pragma unroll
    for (int i = 0; i < 7; i++)
        vpre[i] = *(const uint4*)(vrow + n0c + i * 32 + fq * 8);

    // Q fragment (A-operand)
    U4B8 qa;
    qa.u = *(const uint4*)(qb + ((size_t)bh * Ns + hq * 32 + qbase + fm) * DH + fq * 8);

    // S = Q.K^T in C-layout registers (key = kt*16+fm, query = qbase+fq*4+r)
    f32x4 sv[7];
    #pragma unroll
    for (int i = 0; i < 7; i++) {
        int kt = sel + 2 * i;
        U4B8 kf;
        kf.u = *(const uint4*)(kb + ((size_t)bh * Ns + n0c + kt * 16 + fm) * DH + fq * 8);
        sv[i] = __builtin_amdgcn_mfma_f32_16x16x32_bf16(qa.b, kf.b, (f32x4){0.f,0.f,0.f,0.f}, 0, 0, 0);
    }

    // mask + exp (no max shift) + P write + local sum of rounded values
    float sm[4] = {0.f, 0.f, 0.f, 0.f};
    #pragma unroll
    for (int i = 0; i < 7; i++) {
        int kt = sel + 2 * i;
        int g = n0c + kt * 16 + fm;          // absolute key token
        int gh = g >> 5, gw = g & 31;
        int dhh = gh - hq;
        bool okh = (dhh >= -3) && (dhh <= 3);
        #pragma unroll
        for (int r = 0; r < 4; r++) {
            int qc = qbase + fq * 4 + r;
            int dww = gw - qc;
            bool ok = okh && (dww >= -5) && (dww <= 5);
            float p = ok ? __expf(sv[i][r]) : 0.f;
            unsigned short pu = f2bf(p);
            Pb[qc * PST + kt * 16 + fm] = pu;
            sm[r] += bf2f(pu);
        }
    }
    #pragma unroll
    for (int r = 0; r < 4; r++)
        #pragma unroll
        for (int m = 1; m < 16; m <<= 1)
            sm[r] += __shfl_xor(sm[r], m);
    if (fm == 0) {
        #pragma unroll
        for (int r = 0; r < 4; r++)
            psum[sel][qbase + fq * 4 + r] = sm[r];
    }
    __syncthreads();   // P complete + psum visible (single barrier)

    // O = P.V
    f32x4 acc = (f32x4){0.f, 0.f, 0.f, 0.f};
    #pragma unroll
    for (int i = 0; i < 7; i++) {
        U4B8 pa, vb;
        pa.u = *(const uint4*)&Pb[(qbase + fm) * PST + i * 32 + fq * 8];
        vb.u = vpre[i];
        acc = __builtin_amdgcn_mfma_f32_16x16x32_bf16(pa.b, vb.b, acc, 0, 0, 0);
    }

    #pragma unroll
    for (int r = 0; r < 4; r++) {
        int qq = qbase + fq * 4 + r;
        float inv = 1.f / (psum[0][qq] + psum[1][qq]);
        aob[((size_t)(b * Ns) + hq * 32 + qq) * Es + h * DH + dbase + fm] = f2bf(acc[r] * inv);
    }
}

// ---------------------------------------------------------------------------
// Kernel 3: proj GEMM. A = attn out (bf16), W = proj_w fp32 cast-on-stage.
// ---------------------------------------------------------------------------
__global__ __launch_bounds__(256, 4)
void proj_gemm(const unsigned short* __restrict__ A, const float* __restrict__ W,
               const float* __restrict__ bias, float* __restrict__ out)
{
    __shared__ unsigned short As[64 * GLD];
    __shared__ unsigned short Ws[64 * GLD];

    const int t = threadIdx.x;
    const int m0 = (blockIdx.x & 127) * 64;
    const int j0 = (blockIdx.x >> 7) * 64;

    const int srow = t >> 2;
    const int scol = (t & 3) * 16;

    const int lane = t & 63;
    const int wave = t >> 6;
    const int wm = (wave & 1) * 32;
    const int wn = (wave >> 1) * 32;
    const int fm = lane & 15;
    const int fq = lane >> 4;

    f32x4 acc[2][2];
    #pragma unroll
    for (int i = 0; i < 2; i++)
        #pragma unroll
        for (int j = 0; j < 2; j++)
            acc[i][j] = (f32x4){0.f, 0.f, 0.f, 0.f};

    const unsigned short* Arow = A + (size_t)(m0 + srow) * Es;
    const float* Wrow = W + (size_t)(j0 + srow) * Es;

    for (int k0 = 0; k0 < Es; k0 += 64) {
        uint4 a0 = *(const uint4*)(Arow + k0 + scol);
        uint4 a1 = *(const uint4*)(Arow + k0 + scol + 8);
        float4 w0 = *(const float4*)(Wrow + k0 + scol);
        float4 w1 = *(const float4*)(Wrow + k0 + scol + 4);
        float4 w2 = *(const float4*)(Wrow + k0 + scol + 8);
        float4 w3 = *(const float4*)(Wrow + k0 + scol + 12);
        U4B8 wp0, wp1;
        wp0.s[0] = f2bf(w0.x); wp0.s[1] = f2bf(w0.y); wp0.s[2] = f2bf(w0.z); wp0.s[3] = f2bf(w0.w);
        wp0.s[4] = f2bf(w1.x); wp0.s[5] = f2bf(w1.y); wp0.s[6] = f2bf(w1.z); wp0.s[7] = f2bf(w1.w);
        wp1.s[0] = f2bf(w2.x); wp1.s[1] = f2bf(w2.y); wp1.s[2] = f2bf(w2.z); wp1.s[3] = f2bf(w2.w);
        wp1.s[4] = f2bf(w3.x); wp1.s[5] = f2bf(w3.y); wp1.s[6] = f2bf(w3.z); wp1.s[7] = f2bf(w3.w);
        __syncthreads();
        *(uint4*)&As[srow * GLD + scol]     = a0;
        *(uint4*)&As[srow * GLD + scol + 8] = a1;
        *(uint4*)&Ws[srow * GLD + scol]     = wp0.u;
        *(uint4*)&Ws[srow * GLD + scol + 8] = wp1.u;
        __syncthreads();
        #pragma unroll
        for (int ks = 0; ks < 64; ks += 32) {
            U4B8 af0, af1, bf0, bf1;
            af0.u = *(const uint4*)&As[(wm +      fm) * GLD + ks + fq * 8];
            af1.u = *(const uint4*)&As[(wm + 16 + fm) * GLD + ks + fq * 8];
            bf0.u = *(const uint4*)&Ws[(wn +      fm) * GLD + ks + fq * 8];
            bf1.u = *(const uint4*)&Ws[(wn + 16 + fm) * GLD + ks + fq * 8];
            acc[0][0] = __builtin_amdgcn_mfma_f32_16x16x32_bf16(af0.b, bf0.b, acc[0][0], 0, 0, 0);
            acc[0][1] = __builtin_amdgcn_mfma_f32_16x16x32_bf16(af0.b, bf1.b, acc[0][1], 0, 0, 0);
            acc[1][0] = __builtin_amdgcn_mfma_f32_16x16x32_bf16(af1.b, bf0.b, acc[1][0], 0, 0, 0);
            acc[1][1] = __builtin_amdgcn_mfma_f32_16x16x32_bf16(af1.b, bf1.b, acc[1][1], 0, 0, 0);
        }
    }

    #pragma unroll
    for (int mt = 0; mt < 2; mt++) {
        #pragma unroll
        for (int nt = 0; nt < 2; nt++) {
            #pragma unroll
            for (int r = 0; r < 4; r++) {
                int row = m0 + wm + mt * 16 + fq * 4 + r;
                int col = j0 + wn + nt * 16 + fm;
                out[(size_t)row * Es + col] = acc[mt][nt][r] + bias[col];
            }
        }
    }
}

extern "C" void kernel_launch(void* const* d_in, const int* in_sizes, int n_in,
                              void* d_out, int out_size, void* d_ws, size_t ws_size,
                              hipStream_t stream) {
    const float* x      = (const float*)d_in[0];  // [B,N,E]
    const float* qkv_w  = (const float*)d_in[1];  // [3E,E]
    const float* qkv_b  = (const float*)d_in[2];  // [3E]
    const float* proj_w = (const float*)d_in[3];  // [E,E]
    const float* proj_b = (const float*)d_in[4];  // [E]
    float* out = (float*)d_out;                   // [B,N,E]

    unsigned short* qb  = (unsigned short*)d_ws;  // NX bf16 (q, scaled)
    unsigned short* kb  = qb + NX;                // NX bf16
    unsigned short* vtb = kb + NX;                // NX bf16 (transposed)
    unsigned short* aob = vtb + NX;               // NX bf16 (attn out)

    qkv_gemm<<<dim3(1536), dim3(256), 0, stream>>>(x, qkv_w, qkv_b, qb, kb, vtb);

    attn_mfma2<<<dim3(Bb * NH * 32), dim3(256), 0, stream>>>(qb, kb, vtb, aob);

    proj_gemm<<<dim3(128 * 4), dim3(256), 0, stream>>>(aob, proj_w, proj_b, out);
}

// Round 8
// 99.641 us; speedup vs baseline: 1.0476x; 1.0476x over previous
//
#include <hip/hip_runtime.h>
#include <math.h>

// Problem constants
constexpr int Bb = 8;     // batch
constexpr int Ns = 1024;  // tokens (32x32)
constexpr int Es = 256;   // embed
constexpr int NH = 8;     // heads
constexpr int DH = 32;    // head dim
constexpr int Mrows = Bb * Ns;        // 8192
constexpr int NX = Mrows * Es;        // 2097152
constexpr int NQ = 3 * Es * Es;       // 196608
constexpr int NP = Es * Es;           // 65536

typedef __bf16 bf16x8 __attribute__((ext_vector_type(8)));
typedef float  f32x4  __attribute__((ext_vector_type(4)));
union U4B8 { uint4 u; bf16x8 b; unsigned short s[8]; };

__device__ __forceinline__ unsigned short f2bf(float f) {
    union { float f; unsigned u; } c; c.f = f;
    unsigned r = (c.u + 0x7FFFu + ((c.u >> 16) & 1u)) >> 16;
    return (unsigned short)r;
}
__device__ __forceinline__ float bf2f(unsigned short h) {
    union { unsigned u; float f; } c; c.u = ((unsigned)h) << 16;
    return c.f;
}

#define GLD 72    // gemm LDS row stride (bf16)
#define PST 232   // attn P row stride (bf16)
#define FST 68    // proj fp32 repack row stride (floats)

// ---------------------------------------------------------------------------
// Ledger: persistence -237, 4/CU-barrier -132, no-LDS GEMM -21, attn+proj
// fusion -3, cast-fold -4, occupancy +-0. R4 config (100.4us) is the anchor.
// Fixed harness overhead (R2/R3: dur - mega = 58-70us) => kernels sum ~40us.
// R8: the one unattacked measured pathology — GEMM epilogue scatter stores.
// qkv wrote 16x 2-byte stores/thread; V^T part at 2048B lane stride = 64
// transactions per wave-store. Fix: repack through the ALREADY-ALLOCATED As
// buffer (zero extra LDS), part uniform per block (64|256), then 2 coalesced
// uint4 stores/thread. Same for proj (float4 x4). Inputs to every MFMA are
// byte-identical to R4's verified kernels.
// ---------------------------------------------------------------------------

// Kernel 0: cast x, qkv_w, proj_w fp32 -> bf16 once. 8 elems/thread.
__global__ __launch_bounds__(256, 8)
void cast_all(const float* __restrict__ x, const float* __restrict__ wq,
              const float* __restrict__ wp, unsigned short* __restrict__ xb,
              unsigned short* __restrict__ wqb, unsigned short* __restrict__ wpb)
{
    int i = (blockIdx.x * 256 + threadIdx.x) * 8;
    const float* src; unsigned short* dst;
    if (i < NX)            { src = x  + i;             dst = xb  + i; }
    else if (i < NX + NQ)  { src = wq + (i - NX);      dst = wqb + (i - NX); }
    else                   { src = wp + (i - NX - NQ); dst = wpb + (i - NX - NQ); }
    float4 f0 = *(const float4*)src;
    float4 f1 = *(const float4*)(src + 4);
    U4B8 u;
    u.s[0] = f2bf(f0.x); u.s[1] = f2bf(f0.y); u.s[2] = f2bf(f0.z); u.s[3] = f2bf(f0.w);
    u.s[4] = f2bf(f1.x); u.s[5] = f2bf(f1.y); u.s[6] = f2bf(f1.z); u.s[7] = f2bf(f1.w);
    *(uint4*)dst = u.u;
}

// ---------------------------------------------------------------------------
// Kernel 1: QKV GEMM (R4-verified core) + LDS-repacked coalesced epilogue.
// ---------------------------------------------------------------------------
__global__ __launch_bounds__(256, 8)
void qkv_gemm(const unsigned short* __restrict__ A, const unsigned short* __restrict__ W,
              const float* __restrict__ qkv_b,
              unsigned short* __restrict__ qo, unsigned short* __restrict__ ko,
              unsigned short* __restrict__ vto)
{
    __shared__ unsigned short As[64 * GLD];
    __shared__ unsigned short Ws[64 * GLD];

    const int t = threadIdx.x;
    const int m0 = (blockIdx.x & 127) * 64;
    const int j0 = (blockIdx.x >> 7) * 64;

    const int srow = t >> 2;
    const int scol = (t & 3) * 16;

    const int lane = t & 63;
    const int wave = t >> 6;
    const int wm = (wave & 1) * 32;
    const int wn = (wave >> 1) * 32;
    const int fm = lane & 15;
    const int fq = lane >> 4;

    f32x4 acc[2][2];
    #pragma unroll
    for (int i = 0; i < 2; i++)
        #pragma unroll
        for (int j = 0; j < 2; j++)
            acc[i][j] = (f32x4){0.f, 0.f, 0.f, 0.f};

    const unsigned short* Arow = A + (size_t)(m0 + srow) * Es;
    const unsigned short* Wrow = W + (size_t)(j0 + srow) * Es;

    for (int k0 = 0; k0 < Es; k0 += 64) {
        uint4 a0 = *(const uint4*)(Arow + k0 + scol);
        uint4 a1 = *(const uint4*)(Arow + k0 + scol + 8);
        uint4 w0 = *(const uint4*)(Wrow + k0 + scol);
        uint4 w1 = *(const uint4*)(Wrow + k0 + scol + 8);
        __syncthreads();
        *(uint4*)&As[srow * GLD + scol]     = a0;
        *(uint4*)&As[srow * GLD + scol + 8] = a1;
        *(uint4*)&Ws[srow * GLD + scol]     = w0;
        *(uint4*)&Ws[srow * GLD + scol + 8] = w1;
        __syncthreads();
        #pragma unroll
        for (int ks = 0; ks < 64; ks += 32) {
            U4B8 af0, af1, bf0, bf1;
            af0.u = *(const uint4*)&As[(wm +      fm) * GLD + ks + fq * 8];
            af1.u = *(const uint4*)&As[(wm + 16 + fm) * GLD + ks + fq * 8];
            bf0.u = *(const uint4*)&Ws[(wn +      fm) * GLD + ks + fq * 8];
            bf1.u = *(const uint4*)&Ws[(wn + 16 + fm) * GLD + ks + fq * 8];
            acc[0][0] = __builtin_amdgcn_mfma_f32_16x16x32_bf16(af0.b, bf0.b, acc[0][0], 0, 0, 0);
            acc[0][1] = __builtin_amdgcn_mfma_f32_16x16x32_bf16(af0.b, bf1.b, acc[0][1], 0, 0, 0);
            acc[1][0] = __builtin_amdgcn_mfma_f32_16x16x32_bf16(af1.b, bf0.b, acc[1][0], 0, 0, 0);
            acc[1][1] = __builtin_amdgcn_mfma_f32_16x16x32_bf16(af1.b, bf1.b, acc[1][1], 0, 0, 0);
        }
    }

    // ---- epilogue: repack through As (reused; zero extra LDS) ----
    const int part = j0 >> 8;                 // uniform per block (64 | 256)
    const float qscale = (part == 0) ? 0.0625f : 1.0f;

    __syncthreads();                          // MFMA reads of As done
    #pragma unroll
    for (int mt = 0; mt < 2; mt++)
        #pragma unroll
        for (int nt = 0; nt < 2; nt++)
            #pragma unroll
            for (int r = 0; r < 4; r++) {
                int rl = wm + mt * 16 + fq * 4 + r;    // local row 0..63
                int cl = wn + nt * 16 + fm;            // local col 0..63
                float val = (acc[mt][nt][r] + qkv_b[j0 + cl]) * qscale;
                As[rl * GLD + cl] = f2bf(val);
            }
    __syncthreads();

    const int b  = m0 >> 10;
    const int n0 = m0 & 1023;

    if (part < 2) {
        // q/k: dest (bh, n, d) row-major. 2 coalesced uint4 stores/thread.
        unsigned short* dst = (part == 0) ? qo : ko;
        int rl = t >> 2;                       // 0..63
        #pragma unroll
        for (int s = 0; s < 2; s++) {
            int seg = (t & 3) + s * 4;         // 0..7
            int cl  = seg * 8;
            uint4 v = *(const uint4*)&As[rl * GLD + cl];
            int col  = j0 + cl;
            int head = (col >> 5) & 7;
            int d0   = col & 31;               // 0,8,16,24
            *(uint4*)&dst[((size_t)(b * NH + head) * Ns + (n0 + rl)) * DH + d0] = v;
        }
    } else {
        // v: dest (bh, d, n) transposed. Column-gather from LDS (2-lane/bank
        // broadcast pairs = free), 2 coalesced uint4 stores/thread along n.
        int cl   = t & 63;                     // local col = d index
        int col  = j0 + cl;
        int head = (col >> 5) & 7;
        int d    = col & 31;
        unsigned short* dcol = vto + ((size_t)(b * NH + head) * DH + d) * Ns + n0;
        #pragma unroll
        for (int s = 0; s < 2; s++) {
            int nseg = (t >> 6) + s * 4;       // 0..7
            U4B8 v;
            #pragma unroll
            for (int j = 0; j < 8; j++)
                v.s[j] = As[(nseg * 8 + j) * GLD + cl];
            *(uint4*)&dcol[nseg * 8] = v.u;
        }
    }
}

// ---------------------------------------------------------------------------
// Kernel 2: MFMA attention (byte-identical to R4-verified version).
// ---------------------------------------------------------------------------
__global__ __launch_bounds__(256, 6)
void attn_mfma2(const unsigned short* __restrict__ qb, const unsigned short* __restrict__ kb,
                const unsigned short* __restrict__ vtb, unsigned short* __restrict__ aob)
{
    __shared__ unsigned short Pb[32 * PST];   // 14848 B
    __shared__ float psum[2][32];

    const int blk = blockIdx.x;          // 0..2047
    const int b   = blk & 7;             // XCD-locality: batch pinned to XCD
    const int u   = blk >> 3;
    const int h   = u & 7;
    const int hq  = u >> 3;
    const int bh  = b * NH + h;

    const int t   = threadIdx.x;
    const int lane = t & 63;
    const int w    = t >> 6;
    const int fm = lane & 15;
    const int fq = lane >> 4;

    int n0c = (hq - 3) * 32;
    n0c = n0c < 0 ? 0 : (n0c > Ns - 224 ? Ns - 224 : n0c);

    const int qbase = (w & 1) * 16;      // query 16-tile
    const int sel   = w >> 1;            // key-tile parity
    const int dbase = (w >> 1) * 16;     // PV dim-tile

    // V^T fragment prefetch (B-operand: n=dim, k=key)
    const unsigned short* vrow = vtb + ((size_t)bh * DH + dbase + fm) * Ns;
    uint4 vpre[7];
    #pragma unroll
    for (int i = 0; i < 7; i++)
        vpre[i] = *(const uint4*)(vrow + n0c + i * 32 + fq * 8);

    // Q fragment (A-operand)
    U4B8 qa;
    qa.u = *(const uint4*)(qb + ((size_t)bh * Ns + hq * 32 + qbase + fm) * DH + fq * 8);

    // S = Q.K^T in C-layout registers (key = kt*16+fm, query = qbase+fq*4+r)
    f32x4 sv[7];
    #pragma unroll
    for (int i = 0; i < 7; i++) {
        int kt = sel + 2 * i;
        U4B8 kf;
        kf.u = *(const uint4*)(kb + ((size_t)bh * Ns + n0c + kt * 16 + fm) * DH + fq * 8);
        sv[i] = __builtin_amdgcn_mfma_f32_16x16x32_bf16(qa.b, kf.b, (f32x4){0.f,0.f,0.f,0.f}, 0, 0, 0);
    }

    // mask + exp (no max shift) + P write + local sum of rounded values
    float sm[4] = {0.f, 0.f, 0.f, 0.f};
    #pragma unroll
    for (int i = 0; i < 7; i++) {
        int kt = sel + 2 * i;
        int g = n0c + kt * 16 + fm;          // absolute key token
        int gh = g >> 5, gw = g & 31;
        int dhh = gh - hq;
        bool okh = (dhh >= -3) && (dhh <= 3);
        #pragma unroll
        for (int r = 0; r < 4; r++) {
            int qc = qbase + fq * 4 + r;
            int dww = gw - qc;
            bool ok = okh && (dww >= -5) && (dww <= 5);
            float p = ok ? __expf(sv[i][r]) : 0.f;
            unsigned short pu = f2bf(p);
            Pb[qc * PST + kt * 16 + fm] = pu;
            sm[r] += bf2f(pu);
        }
    }
    #pragma unroll
    for (int r = 0; r < 4; r++)
        #pragma unroll
        for (int m = 1; m < 16; m <<= 1)
            sm[r] += __shfl_xor(sm[r], m);
    if (fm == 0) {
        #pragma unroll
        for (int r = 0; r < 4; r++)
            psum[sel][qbase + fq * 4 + r] = sm[r];
    }
    __syncthreads();   // P complete + psum visible (single barrier)

    // O = P.V
    f32x4 acc = (f32x4){0.f, 0.f, 0.f, 0.f};
    #pragma unroll
    for (int i = 0; i < 7; i++) {
        U4B8 pa, vb;
        pa.u = *(const uint4*)&Pb[(qbase + fm) * PST + i * 32 + fq * 8];
        vb.u = vpre[i];
        acc = __builtin_amdgcn_mfma_f32_16x16x32_bf16(pa.b, vb.b, acc, 0, 0, 0);
    }

    #pragma unroll
    for (int r = 0; r < 4; r++) {
        int qq = qbase + fq * 4 + r;
        float inv = 1.f / (psum[0][qq] + psum[1][qq]);
        aob[((size_t)(b * Ns) + hq * 32 + qq) * Es + h * DH + dbase + fm] = f2bf(acc[r] * inv);
    }
}

// ---------------------------------------------------------------------------
// Kernel 3: proj GEMM (R4-verified core) + float4-repacked epilogue.
// Repack buffer aliases As+Ws as float[64][FST] (17408 B <= 18432 B).
// ---------------------------------------------------------------------------
__global__ __launch_bounds__(256, 8)
void proj_gemm(const unsigned short* __restrict__ A, const unsigned short* __restrict__ Wb,
               const float* __restrict__ bias, float* __restrict__ out)
{
    __shared__ unsigned short As[64 * GLD];
    __shared__ unsigned short Ws[64 * GLD];

    const int t = threadIdx.x;
    const int m0 = (blockIdx.x & 127) * 64;
    const int j0 = (blockIdx.x >> 7) * 64;

    const int srow = t >> 2;
    const int scol = (t & 3) * 16;

    const int lane = t & 63;
    const int wave = t >> 6;
    const int wm = (wave & 1) * 32;
    const int wn = (wave >> 1) * 32;
    const int fm = lane & 15;
    const int fq = lane >> 4;

    f32x4 acc[2][2];
    #pragma unroll
    for (int i = 0; i < 2; i++)
        #pragma unroll
        for (int j = 0; j < 2; j++)
            acc[i][j] = (f32x4){0.f, 0.f, 0.f, 0.f};

    const unsigned short* Arow = A + (size_t)(m0 + srow) * Es;
    const unsigned short* Wrow = Wb + (size_t)(j0 + srow) * Es;

    for (int k0 = 0; k0 < Es; k0 += 64) {
        uint4 a0 = *(const uint4*)(Arow + k0 + scol);
        uint4 a1 = *(const uint4*)(Arow + k0 + scol + 8);
        uint4 w0 = *(const uint4*)(Wrow + k0 + scol);
        uint4 w1 = *(const uint4*)(Wrow + k0 + scol + 8);
        __syncthreads();
        *(uint4*)&As[srow * GLD + scol]     = a0;
        *(uint4*)&As[srow * GLD + scol + 8] = a1;
        *(uint4*)&Ws[srow * GLD + scol]     = w0;
        *(uint4*)&Ws[srow * GLD + scol + 8] = w1;
        __syncthreads();
        #pragma unroll
        for (int ks = 0; ks < 64; ks += 32) {
            U4B8 af0, af1, bf0, bf1;
            af0.u = *(const uint4*)&As[(wm +      fm) * GLD + ks + fq * 8];
            af1.u = *(const uint4*)&As[(wm + 16 + fm) * GLD + ks + fq * 8];
            bf0.u = *(const uint4*)&Ws[(wn +      fm) * GLD + ks + fq * 8];
            bf1.u = *(const uint4*)&Ws[(wn + 16 + fm) * GLD + ks + fq * 8];
            acc[0][0] = __builtin_amdgcn_mfma_f32_16x16x32_bf16(af0.b, bf0.b, acc[0][0], 0, 0, 0);
            acc[0][1] = __builtin_amdgcn_mfma_f32_16x16x32_bf16(af0.b, bf1.b, acc[0][1], 0, 0, 0);
            acc[1][0] = __builtin_amdgcn_mfma_f32_16x16x32_bf16(af1.b, bf0.b, acc[1][0], 0, 0, 0);
            acc[1][1] = __builtin_amdgcn_mfma_f32_16x16x32_bf16(af1.b, bf1.b, acc[1][1], 0, 0, 0);
        }
    }

    // ---- epilogue: repack to float4 stores via aliased As+Ws ----
    float* F = (float*)As;                    // [64][FST], 17408 B
    __syncthreads();                          // MFMA reads done
    #pragma unroll
    for (int mt = 0; mt < 2; mt++)
        #pragma unroll
        for (int nt = 0; nt < 2; nt++)
            #pragma unroll
            for (int r = 0; r < 4; r++) {
                int rl = wm + mt * 16 + fq * 4 + r;
                int cl = wn + nt * 16 + fm;
                F[rl * FST + cl] = acc[mt][nt][r] + bias[j0 + cl];
            }
    __syncthreads();

    int rl = t >> 2;                          // 0..63
    #pragma unroll
    for (int s = 0; s < 4; s++) {
        int seg = (t & 3) + s * 4;            // 0..15
        float4 v = *(const float4*)&F[rl * FST + seg * 4];
        *(float4*)&out[(size_t)(m0 + rl) * Es + j0 + seg * 4] = v;
    }
}

extern "C" void kernel_launch(void* const* d_in, const int* in_sizes, int n_in,
                              void* d_out, int out_size, void* d_ws, size_t ws_size,
                              hipStream_t stream) {
    const float* x      = (const float*)d_in[0];  // [B,N,E]
    const float* qkv_w  = (const float*)d_in[1];  // [3E,E]
    const float* qkv_b  = (const float*)d_in[2];  // [3E]
    const float* proj_w = (const float*)d_in[3];  // [E,E]
    const float* proj_b = (const float*)d_in[4];  // [E]
    float* out = (float*)d_out;                   // [B,N,E]

    unsigned short* xb  = (unsigned short*)d_ws;  // NX bf16
    unsigned short* wqb = xb + NX;                // NQ bf16
    unsigned short* pwb = wqb + NQ;               // NP bf16
    unsigned short* qb  = pwb + NP;               // NX bf16 (q, scaled)
    unsigned short* kb  = qb + NX;                // NX bf16
    unsigned short* vtb = kb + NX;                // NX bf16 (transposed)
    unsigned short* aob = vtb + NX;               // NX bf16 (attn out)

    cast_all<<<dim3((NX + NQ + NP) / 8 / 256), dim3(256), 0, stream>>>(
        x, qkv_w, proj_w, xb, wqb, pwb);

    qkv_gemm<<<dim3(1536), dim3(256), 0, stream>>>(xb, wqb, qkv_b, qb, kb, vtb);

    attn_mfma2<<<dim3(Bb * NH * 32), dim3(256), 0, stream>>>(qb, kb, vtb, aob);

    proj_gemm<<<dim3(128 * 4), dim3(256), 0, stream>>>(aob, pwb, proj_b, out);
}